// Round 1
// baseline (352.490 us; speedup 1.0000x reference)
//
#include <hip/hip_runtime.h>
#include <stdint.h>
#include <math.h>

#define NB 24
#define NC 128
#define NH 8
#define NDK 16
#define NL 512
#define NTOT (24*128*512)

// ---------------- threefry2x32 (JAX-compatible) ----------------
__host__ __device__ inline void tf2x32(uint32_t k0, uint32_t k1, uint32_t& x0, uint32_t& x1) {
  uint32_t ks2 = k0 ^ k1 ^ 0x1BD11BDAu;
  x0 += k0; x1 += k1;
#define TF_R(r) { x0 += x1; x1 = (x1 << r) | (x1 >> (32 - r)); x1 ^= x0; }
  TF_R(13) TF_R(15) TF_R(26) TF_R(6)
  x0 += k1;  x1 += ks2 + 1u;
  TF_R(17) TF_R(29) TF_R(16) TF_R(24)
  x0 += ks2; x1 += k0 + 2u;
  TF_R(13) TF_R(15) TF_R(26) TF_R(6)
  x0 += k0;  x1 += k1 + 3u;
  TF_R(17) TF_R(29) TF_R(16) TF_R(24)
  x0 += k1;  x1 += ks2 + 4u;
  TF_R(13) TF_R(15) TF_R(26) TF_R(6)
  x0 += ks2; x1 += k0 + 5u;
#undef TF_R
}

// partitionable threefry random bits: per flat element idx, bits = x0^x1 of
// threefry2x32(key, (0, idx)); uniform = bitcast((bits>>9)|0x3f800000)-1; keep = u < 0.9
__device__ inline float drop_scale(uint32_t k0, uint32_t k1, uint32_t idx) {
  uint32_t x0 = 0u, x1 = idx;
  tf2x32(k0, k1, x0, x1);
  uint32_t bits = x0 ^ x1;
  float u = __uint_as_float((bits >> 9) | 0x3f800000u) - 1.0f;
  return (u < 0.9f) ? (1.0f / 0.9f) : 0.0f;
}

// ---------------- positional encoding + add ----------------
__global__ __launch_bounds__(256) void pos_add_kernel(const float* __restrict__ x,
                                                      float* __restrict__ out) {
  int idx = blockIdx.x * 256 + threadIdx.x;
  int l = idx & (NL - 1);
  int c = (idx >> 9) & (NC - 1);
  int ce = c & ~1;
  double base = exp(-(double)ce * 9.210340371976184 / 128.0); // ln(10000)
  float freq = (c & 1) ? -(float)base : (float)base;
  float phase = (c & 1) ? (float)(M_PI / 2.0) : 0.0f;
  float pe = sinf(sinf((float)l * freq + phase));
  out[idx] = x[idx] + pe;
}

// ---------------- fused layernorm (+ optional depthwise conv) ----------------
// one wave (64 threads) per (b,c) row of length 512
template<bool DO_CONV>
__global__ __launch_bounds__(64) void norm_dw_kernel(const float* __restrict__ in,
                                                     float* __restrict__ outp,
                                                     const float* __restrict__ dww,
                                                     const float* __restrict__ dwb) {
  int row = blockIdx.x;           // b*NC + c
  int c = row & (NC - 1);
  int t = threadIdx.x;
  const float* rp = in + (size_t)row * NL;
  float4 v0 = ((const float4*)rp)[t * 2];
  float4 v1 = ((const float4*)rp)[t * 2 + 1];
  float xr[8] = {v0.x, v0.y, v0.z, v0.w, v1.x, v1.y, v1.z, v1.w};
  float s = 0.f;
#pragma unroll
  for (int j = 0; j < 8; ++j) s += xr[j];
#pragma unroll
  for (int off = 32; off >= 1; off >>= 1) s += __shfl_xor(s, off);
  float mean = s * (1.0f / 512.0f);
  float sq = 0.f;
#pragma unroll
  for (int j = 0; j < 8; ++j) { xr[j] -= mean; sq += xr[j] * xr[j]; }
#pragma unroll
  for (int off = 32; off >= 1; off >>= 1) sq += __shfl_xor(sq, off);
  float inv = 1.0f / (sqrtf(sq * (1.0f / 511.0f)) + 1e-6f);

  if (!DO_CONV) {
    float4 o0 = make_float4(xr[0]*inv, xr[1]*inv, xr[2]*inv, xr[3]*inv);
    float4 o1 = make_float4(xr[4]*inv, xr[5]*inv, xr[6]*inv, xr[7]*inv);
    float4* op = (float4*)(outp + (size_t)row * NL);
    op[t * 2] = o0; op[t * 2 + 1] = o1;
  } else {
    __shared__ float rb[NL + 6];
    if (t < 3) { rb[t] = 0.f; rb[NL + 3 + t] = 0.f; }
#pragma unroll
    for (int j = 0; j < 8; ++j) rb[3 + t * 8 + j] = xr[j] * inv;
    __syncthreads();
    float w[7];
#pragma unroll
    for (int u = 0; u < 7; ++u) w[u] = dww[c * 7 + u];
    float bias = dwb[c];
    float* op = outp + (size_t)row * NL + t * 8;
#pragma unroll
    for (int j = 0; j < 8; ++j) {
      int l = t * 8 + j;
      float o = bias;
#pragma unroll
      for (int u = 0; u < 7; ++u) o += rb[l + u] * w[u];
      op[j] = o;
    }
  }
}

// ---------------- per-batch 128x128 @ 128x512 GEMM with fused epilogues ----------------
// EPI: 0 = bias+relu+resid+dropout (pointwise conv)
//      1 = resid+dropout            (Wo)
//      2 = relu+resid+dropout       (final W)
template<int EPI, bool A_PER_B>
__global__ __launch_bounds__(256) void gemm128_kernel(const float* __restrict__ A,
                                                      const float* __restrict__ X,
                                                      float* __restrict__ Y,
                                                      const float* __restrict__ bias,
                                                      const float* __restrict__ resid,
                                                      uint32_t k0, uint32_t k1) {
  __shared__ float As[64][129];
  __shared__ float Xs[128][68];
  int b  = blockIdx.z;
  int m0 = blockIdx.y * 64;
  int l0 = blockIdx.x * 64;
  int t  = threadIdx.x;
  const float* Ab = A + (A_PER_B ? (size_t)b * NC * NC : 0);
  const float* Xb = X + (size_t)b * NC * NL;

#pragma unroll
  for (int i = 0; i < 8; ++i) {           // A tile: 64 x 128
    int id = t + i * 256;                 // float4 id (2048 total)
    int r = id >> 5;
    int c4 = (id & 31) << 2;
    float4 v = *(const float4*)&Ab[(size_t)(m0 + r) * NC + c4];
    As[r][c4] = v.x; As[r][c4+1] = v.y; As[r][c4+2] = v.z; As[r][c4+3] = v.w;
  }
#pragma unroll
  for (int i = 0; i < 8; ++i) {           // X tile: 128 x 64
    int id = t + i * 256;
    int r = id >> 4;
    int c4 = (id & 15) << 2;
    float4 v = *(const float4*)&Xb[(size_t)r * NL + l0 + c4];
    Xs[r][c4] = v.x; Xs[r][c4+1] = v.y; Xs[r][c4+2] = v.z; Xs[r][c4+3] = v.w;
  }
  __syncthreads();

  int tm = t >> 4, tl = t & 15;
  float acc[4][4] = {};
#pragma unroll 4
  for (int k = 0; k < 128; ++k) {
    float a0 = As[tm*4+0][k], a1 = As[tm*4+1][k], a2 = As[tm*4+2][k], a3 = As[tm*4+3][k];
    float4 xv = *(const float4*)&Xs[k][tl << 2];
    acc[0][0] += a0*xv.x; acc[0][1] += a0*xv.y; acc[0][2] += a0*xv.z; acc[0][3] += a0*xv.w;
    acc[1][0] += a1*xv.x; acc[1][1] += a1*xv.y; acc[1][2] += a1*xv.z; acc[1][3] += a1*xv.w;
    acc[2][0] += a2*xv.x; acc[2][1] += a2*xv.y; acc[2][2] += a2*xv.z; acc[2][3] += a2*xv.w;
    acc[3][0] += a3*xv.x; acc[3][1] += a3*xv.y; acc[3][2] += a3*xv.z; acc[3][3] += a3*xv.w;
  }

#pragma unroll
  for (int i = 0; i < 4; ++i) {
    int m = m0 + tm * 4 + i;
    float bv = (EPI == 0) ? bias[m] : 0.0f;
#pragma unroll
    for (int j = 0; j < 4; ++j) {
      int l = l0 + tl * 4 + j;
      float val = acc[i][j] + bv;
      if (EPI == 0 || EPI == 2) val = fmaxf(val, 0.0f);
      size_t idx = ((size_t)b * NC + m) * NL + l;
      float v2 = resid[idx] + val;
      float ds = drop_scale(k0, k1, (uint32_t)idx);
      Y[idx] = (ds == 0.0f) ? 0.0f : (v2 / 0.9f);
    }
  }
}

// ---------------- stacked QKV projection: (3*H*DK=384 x 128) @ (128 x 512) per b ----------------
__global__ __launch_bounds__(256) void qkv_kernel(const float* __restrict__ Wq,
                                                  const float* __restrict__ Wk,
                                                  const float* __restrict__ Wv,
                                                  const float* __restrict__ X,
                                                  float* __restrict__ out) {
  __shared__ float As[64][129];
  __shared__ float Xs[128][68];
  int b  = blockIdx.z;
  int m0 = blockIdx.y * 64;     // global row in [0,384)
  int l0 = blockIdx.x * 64;
  int t  = threadIdx.x;
  const float* Xb = X + (size_t)b * NC * NL;

#pragma unroll
  for (int i = 0; i < 8; ++i) {
    int id = t + i * 256;
    int r = id >> 5;
    int c4 = (id & 31) << 2;
    int gr = m0 + r;
    int sel = gr >> 7, w = gr & 127, h = w >> 4, kk = w & 15;
    const float* Wp = (sel == 0) ? Wq : ((sel == 1) ? Wk : Wv);
    const float* rowp = Wp + (((size_t)h * NB + b) * NDK + kk) * NC;
    float4 v = *(const float4*)&rowp[c4];
    As[r][c4] = v.x; As[r][c4+1] = v.y; As[r][c4+2] = v.z; As[r][c4+3] = v.w;
  }
#pragma unroll
  for (int i = 0; i < 8; ++i) {
    int id = t + i * 256;
    int r = id >> 4;
    int c4 = (id & 15) << 2;
    float4 v = *(const float4*)&Xb[(size_t)r * NL + l0 + c4];
    Xs[r][c4] = v.x; Xs[r][c4+1] = v.y; Xs[r][c4+2] = v.z; Xs[r][c4+3] = v.w;
  }
  __syncthreads();

  int tm = t >> 4, tl = t & 15;
  float acc[4][4] = {};
#pragma unroll 4
  for (int k = 0; k < 128; ++k) {
    float a0 = As[tm*4+0][k], a1 = As[tm*4+1][k], a2 = As[tm*4+2][k], a3 = As[tm*4+3][k];
    float4 xv = *(const float4*)&Xs[k][tl << 2];
    acc[0][0] += a0*xv.x; acc[0][1] += a0*xv.y; acc[0][2] += a0*xv.z; acc[0][3] += a0*xv.w;
    acc[1][0] += a1*xv.x; acc[1][1] += a1*xv.y; acc[1][2] += a1*xv.z; acc[1][3] += a1*xv.w;
    acc[2][0] += a2*xv.x; acc[2][1] += a2*xv.y; acc[2][2] += a2*xv.z; acc[2][3] += a2*xv.w;
    acc[3][0] += a3*xv.x; acc[3][1] += a3*xv.y; acc[3][2] += a3*xv.z; acc[3][3] += a3*xv.w;
  }

#pragma unroll
  for (int i = 0; i < 4; ++i) {
    int gr = m0 + tm * 4 + i;
    int sel = gr >> 7, w = gr & 127, h = w >> 4, kk = w & 15;
    size_t base = (size_t)sel * NTOT + (((size_t)h * NB + b) * NDK + kk) * NL;
#pragma unroll
    for (int j = 0; j < 4; ++j) out[base + l0 + tl * 4 + j] = acc[i][j];
  }
}

// ---------------- fused attention: per (h,b), softmax over query axis i ----------------
// s[i,j] = (1/4) * sum_k q[k,i] k[k,j];  p = softmax_i;  head[v,j] = sum_i v[v,i] p[i,j]
__global__ __launch_bounds__(512) void attn_kernel(const float* __restrict__ qkv,
                                                   float* __restrict__ headbuf) {
  __shared__ float Qs[16][512];
  __shared__ float Vs[16][512];
  int hb = blockIdx.x;          // h*NB + b
  int h = hb / NB, b = hb % NB;
  const float* qp = qkv + (size_t)hb * NDK * NL;
  const float* kp = qkv + (size_t)NTOT + (size_t)hb * NDK * NL;
  const float* vp = qkv + (size_t)2 * NTOT + (size_t)hb * NDK * NL;
  for (int i = threadIdx.x; i < NDK * NL / 4; i += 512) {
    ((float4*)&Qs[0][0])[i] = ((const float4*)qp)[i];
    ((float4*)&Vs[0][0])[i] = ((const float4*)vp)[i];
  }
  __syncthreads();

  int j = threadIdx.x;
  float kc[16];
#pragma unroll
  for (int v = 0; v < 16; ++v) kc[v] = kp[v * NL + j];

  float m = -INFINITY, lsum = 0.f;
  float acc[16] = {};
  for (int i = 0; i < NL; ++i) {
    float s = 0.f;
#pragma unroll
    for (int v = 0; v < 16; ++v) s += Qs[v][i] * kc[v];
    s *= 0.25f;
    if (s > m) {
      float corr = __expf(m - s);
      lsum = lsum * corr + 1.0f;
#pragma unroll
      for (int v = 0; v < 16; ++v) acc[v] = acc[v] * corr + Vs[v][i];
      m = s;
    } else {
      float p = __expf(s - m);
      lsum += p;
#pragma unroll
      for (int v = 0; v < 16; ++v) acc[v] += p * Vs[v][i];
    }
  }
  float invl = 1.0f / lsum;
  float* hp = headbuf + ((size_t)b * NC + h * NDK) * NL + j;
#pragma unroll
  for (int v = 0; v < 16; ++v) hp[v * NL] = acc[v] * invl;
}

// ---------------- launch ----------------
extern "C" void kernel_launch(void* const* d_in, const int* in_sizes, int n_in,
                              void* d_out, int out_size, void* d_ws, size_t ws_size,
                              hipStream_t stream) {
  (void)in_sizes; (void)n_in; (void)out_size; (void)ws_size;
  const float* x    = (const float*)d_in[0];
  const float* dw_w = (const float*)d_in[1];
  const float* dw_b = (const float*)d_in[2];
  const float* pw_w = (const float*)d_in[3];
  const float* pw_b = (const float*)d_in[4];
  const float* Wq   = (const float*)d_in[5];
  const float* Wk   = (const float*)d_in[6];
  const float* Wv   = (const float*)d_in[7];
  const float* Wo   = (const float*)d_in[8];
  const float* W    = (const float*)d_in[9];
  float* out = (float*)d_out;

  const size_t N = NTOT;
  float* cur  = (float*)d_ws;      // running out / res
  float* bufA = cur + N;           // normalized (xn)
  float* bufB = bufA + N;          // dwconv result / head buffer
  float* qkv  = bufB + N;          // 3*N

  // host-side fold_in(key(7), i) for i = 0..5
  uint32_t fk0[6], fk1[6];
  for (int i = 0; i < 6; ++i) {
    uint32_t a = 0u, bb = (uint32_t)i;
    tf2x32(0u, 7u, a, bb);
    fk0[i] = a; fk1[i] = bb;
  }

  pos_add_kernel<<<NTOT / 256, 256, 0, stream>>>(x, cur);

  for (int ci = 0; ci < 4; ++ci) {
    norm_dw_kernel<true><<<NB * NC, 64, 0, stream>>>(cur, bufB, dw_w + ci * NC * 7, dw_b + ci * NC);
    gemm128_kernel<0, false><<<dim3(8, 2, NB), 256, 0, stream>>>(
        pw_w + (size_t)ci * NC * NC, bufB, cur, pw_b + ci * NC, cur, fk0[ci], fk1[ci]);
  }

  norm_dw_kernel<false><<<NB * NC, 64, 0, stream>>>(cur, bufA, nullptr, nullptr);
  qkv_kernel<<<dim3(8, 6, NB), 256, 0, stream>>>(Wq, Wk, Wv, bufA, qkv);
  attn_kernel<<<NH * NB, 512, 0, stream>>>(qkv, bufB);
  gemm128_kernel<1, true><<<dim3(8, 2, NB), 256, 0, stream>>>(
      Wo, bufB, cur, nullptr, cur, fk0[4], fk1[4]);

  norm_dw_kernel<false><<<NB * NC, 64, 0, stream>>>(cur, bufA, nullptr, nullptr);
  gemm128_kernel<2, true><<<dim3(8, 2, NB), 256, 0, stream>>>(
      W, bufA, out, nullptr, cur, fk0[5], fk1[5]);
}

// Round 3
// 275.997 us; speedup vs baseline: 1.2772x; 1.2772x over previous
//
#include <hip/hip_runtime.h>
#include <stdint.h>
#include <math.h>

#define NB 24
#define NC 128
#define NH 8
#define NDK 16
#define NL 512
#define NTOT (24*128*512)

// ---------------- threefry2x32 (JAX-compatible) ----------------
__host__ __device__ inline void tf2x32(uint32_t k0, uint32_t k1, uint32_t& x0, uint32_t& x1) {
  uint32_t ks2 = k0 ^ k1 ^ 0x1BD11BDAu;
  x0 += k0; x1 += k1;
#define TF_R(r) { x0 += x1; x1 = (x1 << r) | (x1 >> (32 - r)); x1 ^= x0; }
  TF_R(13) TF_R(15) TF_R(26) TF_R(6)
  x0 += k1;  x1 += ks2 + 1u;
  TF_R(17) TF_R(29) TF_R(16) TF_R(24)
  x0 += ks2; x1 += k0 + 2u;
  TF_R(13) TF_R(15) TF_R(26) TF_R(6)
  x0 += k0;  x1 += k1 + 3u;
  TF_R(17) TF_R(29) TF_R(16) TF_R(24)
  x0 += k1;  x1 += ks2 + 4u;
  TF_R(13) TF_R(15) TF_R(26) TF_R(6)
  x0 += ks2; x1 += k0 + 5u;
#undef TF_R
}

__device__ inline float drop_scale(uint32_t k0, uint32_t k1, uint32_t idx) {
  uint32_t x0 = 0u, x1 = idx;
  tf2x32(k0, k1, x0, x1);
  uint32_t bits = x0 ^ x1;
  float u = __uint_as_float((bits >> 9) | 0x3f800000u) - 1.0f;
  return (u < 0.9f) ? (1.0f / 0.9f) : 0.0f;
}

// ---------------- positional encoding + add ----------------
__global__ __launch_bounds__(256) void pos_add_kernel(const float* __restrict__ x,
                                                      float* __restrict__ out) {
  int idx = blockIdx.x * 256 + threadIdx.x;
  int l = idx & (NL - 1);
  int c = (idx >> 9) & (NC - 1);
  int ce = c & ~1;
  double base = exp(-(double)ce * 9.210340371976184 / 128.0); // ln(10000)
  float freq = (c & 1) ? -(float)base : (float)base;
  float phase = (c & 1) ? (float)(M_PI / 2.0) : 0.0f;
  float pe = sinf(sinf((float)l * freq + phase));
  out[idx] = x[idx] + pe;
}

// ---------------- fused layernorm (+ optional depthwise conv) ----------------
template<bool DO_CONV>
__global__ __launch_bounds__(64) void norm_dw_kernel(const float* __restrict__ in,
                                                     float* __restrict__ outp,
                                                     const float* __restrict__ dww,
                                                     const float* __restrict__ dwb) {
  int row = blockIdx.x;           // b*NC + c
  int c = row & (NC - 1);
  int t = threadIdx.x;
  const float* rp = in + (size_t)row * NL;
  float4 v0 = ((const float4*)rp)[t * 2];
  float4 v1 = ((const float4*)rp)[t * 2 + 1];
  float xr[8] = {v0.x, v0.y, v0.z, v0.w, v1.x, v1.y, v1.z, v1.w};
  float s = 0.f;
#pragma unroll
  for (int j = 0; j < 8; ++j) s += xr[j];
#pragma unroll
  for (int off = 32; off >= 1; off >>= 1) s += __shfl_xor(s, off);
  float mean = s * (1.0f / 512.0f);
  float sq = 0.f;
#pragma unroll
  for (int j = 0; j < 8; ++j) { xr[j] -= mean; sq += xr[j] * xr[j]; }
#pragma unroll
  for (int off = 32; off >= 1; off >>= 1) sq += __shfl_xor(sq, off);
  float inv = 1.0f / (sqrtf(sq * (1.0f / 511.0f)) + 1e-6f);

  if (!DO_CONV) {
    float4 o0 = make_float4(xr[0]*inv, xr[1]*inv, xr[2]*inv, xr[3]*inv);
    float4 o1 = make_float4(xr[4]*inv, xr[5]*inv, xr[6]*inv, xr[7]*inv);
    float4* op = (float4*)(outp + (size_t)row * NL);
    op[t * 2] = o0; op[t * 2 + 1] = o1;
  } else {
    __shared__ float rb[NL + 6];
    if (t < 3) { rb[t] = 0.f; rb[NL + 3 + t] = 0.f; }
#pragma unroll
    for (int j = 0; j < 8; ++j) rb[3 + t * 8 + j] = xr[j] * inv;
    __syncthreads();
    float w[7];
#pragma unroll
    for (int u = 0; u < 7; ++u) w[u] = dww[c * 7 + u];
    float bias = dwb[c];
    float* op = outp + (size_t)row * NL + t * 8;
#pragma unroll
    for (int j = 0; j < 8; ++j) {
      int l = t * 8 + j;
      float o = bias;
#pragma unroll
      for (int u = 0; u < 7; ++u) o += rb[l + u] * w[u];
      op[j] = o;
    }
  }
}

// ---------------- per-batch 128x128 @ 128x512 GEMM with fused epilogues ----------------
template<int EPI, bool A_PER_B>
__global__ __launch_bounds__(256) void gemm128_kernel(const float* __restrict__ A,
                                                      const float* __restrict__ X,
                                                      float* __restrict__ Y,
                                                      const float* __restrict__ bias,
                                                      const float* __restrict__ resid,
                                                      uint32_t k0, uint32_t k1) {
  __shared__ float As[64][129];
  __shared__ float Xs[128][68];
  int b  = blockIdx.z;
  int m0 = blockIdx.y * 64;
  int l0 = blockIdx.x * 64;
  int t  = threadIdx.x;
  const float* Ab = A + (A_PER_B ? (size_t)b * NC * NC : 0);
  const float* Xb = X + (size_t)b * NC * NL;

#pragma unroll
  for (int i = 0; i < 8; ++i) {
    int id = t + i * 256;
    int r = id >> 5;
    int c4 = (id & 31) << 2;
    float4 v = *(const float4*)&Ab[(size_t)(m0 + r) * NC + c4];
    As[r][c4] = v.x; As[r][c4+1] = v.y; As[r][c4+2] = v.z; As[r][c4+3] = v.w;
  }
#pragma unroll
  for (int i = 0; i < 8; ++i) {
    int id = t + i * 256;
    int r = id >> 4;
    int c4 = (id & 15) << 2;
    float4 v = *(const float4*)&Xb[(size_t)r * NL + l0 + c4];
    Xs[r][c4] = v.x; Xs[r][c4+1] = v.y; Xs[r][c4+2] = v.z; Xs[r][c4+3] = v.w;
  }
  __syncthreads();

  int tm = t >> 4, tl = t & 15;
  float acc[4][4] = {};
#pragma unroll 4
  for (int k = 0; k < 128; ++k) {
    float a0 = As[tm*4+0][k], a1 = As[tm*4+1][k], a2 = As[tm*4+2][k], a3 = As[tm*4+3][k];
    float4 xv = *(const float4*)&Xs[k][tl << 2];
    acc[0][0] += a0*xv.x; acc[0][1] += a0*xv.y; acc[0][2] += a0*xv.z; acc[0][3] += a0*xv.w;
    acc[1][0] += a1*xv.x; acc[1][1] += a1*xv.y; acc[1][2] += a1*xv.z; acc[1][3] += a1*xv.w;
    acc[2][0] += a2*xv.x; acc[2][1] += a2*xv.y; acc[2][2] += a2*xv.z; acc[2][3] += a2*xv.w;
    acc[3][0] += a3*xv.x; acc[3][1] += a3*xv.y; acc[3][2] += a3*xv.z; acc[3][3] += a3*xv.w;
  }

#pragma unroll
  for (int i = 0; i < 4; ++i) {
    int m = m0 + tm * 4 + i;
    float bv = (EPI == 0) ? bias[m] : 0.0f;
#pragma unroll
    for (int j = 0; j < 4; ++j) {
      int l = l0 + tl * 4 + j;
      float val = acc[i][j] + bv;
      if (EPI == 0 || EPI == 2) val = fmaxf(val, 0.0f);
      size_t idx = ((size_t)b * NC + m) * NL + l;
      float v2 = resid[idx] + val;
      float ds = drop_scale(k0, k1, (uint32_t)idx);
      Y[idx] = (ds == 0.0f) ? 0.0f : (v2 / 0.9f);
    }
  }
}

// ---------------- stacked QKV projection ----------------
__global__ __launch_bounds__(256) void qkv_kernel(const float* __restrict__ Wq,
                                                  const float* __restrict__ Wk,
                                                  const float* __restrict__ Wv,
                                                  const float* __restrict__ X,
                                                  float* __restrict__ out) {
  __shared__ float As[64][129];
  __shared__ float Xs[128][68];
  int b  = blockIdx.z;
  int m0 = blockIdx.y * 64;
  int l0 = blockIdx.x * 64;
  int t  = threadIdx.x;
  const float* Xb = X + (size_t)b * NC * NL;

#pragma unroll
  for (int i = 0; i < 8; ++i) {
    int id = t + i * 256;
    int r = id >> 5;
    int c4 = (id & 31) << 2;
    int gr = m0 + r;
    int sel = gr >> 7, w = gr & 127, h = w >> 4, kk = w & 15;
    const float* Wp = (sel == 0) ? Wq : ((sel == 1) ? Wk : Wv);
    const float* rowp = Wp + (((size_t)h * NB + b) * NDK + kk) * NC;
    float4 v = *(const float4*)&rowp[c4];
    As[r][c4] = v.x; As[r][c4+1] = v.y; As[r][c4+2] = v.z; As[r][c4+3] = v.w;
  }
#pragma unroll
  for (int i = 0; i < 8; ++i) {
    int id = t + i * 256;
    int r = id >> 4;
    int c4 = (id & 15) << 2;
    float4 v = *(const float4*)&Xb[(size_t)r * NL + l0 + c4];
    Xs[r][c4] = v.x; Xs[r][c4+1] = v.y; Xs[r][c4+2] = v.z; Xs[r][c4+3] = v.w;
  }
  __syncthreads();

  int tm = t >> 4, tl = t & 15;
  float acc[4][4] = {};
#pragma unroll 4
  for (int k = 0; k < 128; ++k) {
    float a0 = As[tm*4+0][k], a1 = As[tm*4+1][k], a2 = As[tm*4+2][k], a3 = As[tm*4+3][k];
    float4 xv = *(const float4*)&Xs[k][tl << 2];
    acc[0][0] += a0*xv.x; acc[0][1] += a0*xv.y; acc[0][2] += a0*xv.z; acc[0][3] += a0*xv.w;
    acc[1][0] += a1*xv.x; acc[1][1] += a1*xv.y; acc[1][2] += a1*xv.z; acc[1][3] += a1*xv.w;
    acc[2][0] += a2*xv.x; acc[2][1] += a2*xv.y; acc[2][2] += a2*xv.z; acc[2][3] += a2*xv.w;
    acc[3][0] += a3*xv.x; acc[3][1] += a3*xv.y; acc[3][2] += a3*xv.z; acc[3][3] += a3*xv.w;
  }

#pragma unroll
  for (int i = 0; i < 4; ++i) {
    int gr = m0 + tm * 4 + i;
    int sel = gr >> 7, w = gr & 127, h = w >> 4, kk = w & 15;
    size_t base = (size_t)sel * NTOT + (((size_t)h * NB + b) * NDK + kk) * NL;
#pragma unroll
    for (int j = 0; j < 4; ++j) out[base + l0 + tl * 4 + j] = acc[i][j];
  }
}

// ---------------- fused attention v2 ----------------
// softmax over query axis i, per key column j.
// grid: 768 blocks = (h*NB+b) * 4 j-quarters; 512 threads = 128 j x 4 i-quarters.
// Two-pass (max, then exp+acc) per i-quarter, branch-free; 4 partials merged in LDS.
__device__ inline float dot4f(const float4 a, const float4 b) {
  return fmaf(a.x, b.x, fmaf(a.y, b.y, fmaf(a.z, b.z, a.w * b.w)));
}
__device__ inline void fma4f(float4& a, float p, const float4 v) {
  a.x = fmaf(p, v.x, a.x); a.y = fmaf(p, v.y, a.y);
  a.z = fmaf(p, v.z, a.z); a.w = fmaf(p, v.w, a.w);
}

__global__ __launch_bounds__(512) void attn_kernel(const float* __restrict__ qkv,
                                                   float* __restrict__ headbuf) {
  __shared__ union {
    struct { float Qt[512][16]; float Vt[512][16]; } s;                      // 64 KB
    struct { float pm[4][128]; float pl[4][128]; float pacc[4][128][20]; } c; // 44 KB
  } u;
  int bx = blockIdx.x;
  int hb = bx >> 2, jq = bx & 3;
  int h = hb / NB, b = hb % NB;
  const float* qp = qkv + (size_t)hb * NDK * NL;
  const float* kp = qp + NTOT;
  const float* vp = qp + 2 * NTOT;
  int t = threadIdx.x;

  // stage Q,V transposed [i][k], k-groups XOR-swizzled by (i&3) to spread banks
  for (int n = 0; n < 16; ++n) {
    int e = n * 512 + t;
    int k = e >> 9, i = e & 511;
    int ks = (k & 3) | ((((k >> 2) ^ i) & 3) << 2);
    u.s.Qt[i][ks] = qp[e];
    u.s.Vt[i][ks] = vp[e];
  }
  __syncthreads();

  int j = t & 127, iq = t >> 7;
  int jg = jq * 128 + j;
  float4 kg[4];
#pragma unroll
  for (int g = 0; g < 4; ++g)
    kg[g] = make_float4(kp[(4*g+0)*NL + jg], kp[(4*g+1)*NL + jg],
                        kp[(4*g+2)*NL + jg], kp[(4*g+3)*NL + jg]);

  const int i0 = iq * 128;
  // pass 1: max over this i-quarter
  float m = -INFINITY;
  for (int ib = i0; ib < i0 + 128; ib += 4) {
#pragma unroll
    for (int d = 0; d < 4; ++d) {   // i = ib+d, swizzle = d (ib % 4 == 0)
      const float4* qr = (const float4*)u.s.Qt[ib + d];
      float s = dot4f(qr[0], kg[0 ^ d]) + dot4f(qr[1], kg[1 ^ d])
              + dot4f(qr[2], kg[2 ^ d]) + dot4f(qr[3], kg[3 ^ d]);
      m = fmaxf(m, s * 0.25f);
    }
  }
  // pass 2: exp + accumulate (s recomputed with identical FMA order -> s-m <= 0 exactly)
  float l = 0.0f;
  float4 accL[4] = {make_float4(0,0,0,0), make_float4(0,0,0,0),
                    make_float4(0,0,0,0), make_float4(0,0,0,0)};
  for (int ib = i0; ib < i0 + 128; ib += 4) {
#pragma unroll
    for (int d = 0; d < 4; ++d) {
      const float4* qr = (const float4*)u.s.Qt[ib + d];
      const float4* vr = (const float4*)u.s.Vt[ib + d];
      float s = dot4f(qr[0], kg[0 ^ d]) + dot4f(qr[1], kg[1 ^ d])
              + dot4f(qr[2], kg[2 ^ d]) + dot4f(qr[3], kg[3 ^ d]);
      float p = __expf(fmaf(s, 0.25f, -m));
      l += p;
      float4 v0 = vr[0], v1 = vr[1], v2 = vr[2], v3 = vr[3];
      fma4f(accL[0 ^ d], p, v0);
      fma4f(accL[1 ^ d], p, v1);
      fma4f(accL[2 ^ d], p, v2);
      fma4f(accL[3 ^ d], p, v3);
    }
  }
  __syncthreads();   // staging buffers dead; union reuse
  u.c.pm[iq][j] = m;
  u.c.pl[iq][j] = l;
  {
    float4* pr = (float4*)u.c.pacc[iq][j];
    pr[0] = accL[0]; pr[1] = accL[1]; pr[2] = accL[2]; pr[3] = accL[3];
  }
  __syncthreads();

  // combine: thread (j, g=iq) merges 4 partials for v in [4g, 4g+4)
  int g = iq;
  float m0 = u.c.pm[0][j], m1 = u.c.pm[1][j], m2 = u.c.pm[2][j], m3 = u.c.pm[3][j];
  float M = fmaxf(fmaxf(m0, m1), fmaxf(m2, m3));
  float e0 = __expf(m0 - M), e1 = __expf(m1 - M), e2 = __expf(m2 - M), e3 = __expf(m3 - M);
  float L = u.c.pl[0][j]*e0 + u.c.pl[1][j]*e1 + u.c.pl[2][j]*e2 + u.c.pl[3][j]*e3;
  float invL = 1.0f / L;
  float4 h0 = ((const float4*)u.c.pacc[0][j])[g];
  float4 h1 = ((const float4*)u.c.pacc[1][j])[g];
  float4 h2 = ((const float4*)u.c.pacc[2][j])[g];
  float4 h3 = ((const float4*)u.c.pacc[3][j])[g];
  float* hp = headbuf + ((size_t)b * NC + h * NDK + g * 4) * NL + jg;
  hp[0*NL] = (h0.x*e0 + h1.x*e1 + h2.x*e2 + h3.x*e3) * invL;
  hp[1*NL] = (h0.y*e0 + h1.y*e1 + h2.y*e2 + h3.y*e3) * invL;
  hp[2*NL] = (h0.z*e0 + h1.z*e1 + h2.z*e2 + h3.z*e3) * invL;
  hp[3*NL] = (h0.w*e0 + h1.w*e1 + h2.w*e2 + h3.w*e3) * invL;
}

// ---------------- launch ----------------
extern "C" void kernel_launch(void* const* d_in, const int* in_sizes, int n_in,
                              void* d_out, int out_size, void* d_ws, size_t ws_size,
                              hipStream_t stream) {
  (void)in_sizes; (void)n_in; (void)out_size; (void)ws_size;
  const float* x    = (const float*)d_in[0];
  const float* dw_w = (const float*)d_in[1];
  const float* dw_b = (const float*)d_in[2];
  const float* pw_w = (const float*)d_in[3];
  const float* pw_b = (const float*)d_in[4];
  const float* Wq   = (const float*)d_in[5];
  const float* Wk   = (const float*)d_in[6];
  const float* Wv   = (const float*)d_in[7];
  const float* Wo   = (const float*)d_in[8];
  const float* W    = (const float*)d_in[9];
  float* out = (float*)d_out;

  const size_t N = NTOT;
  float* cur  = (float*)d_ws;
  float* bufA = cur + N;
  float* bufB = bufA + N;
  float* qkv  = bufB + N;     // 3*N

  uint32_t fk0[6], fk1[6];
  for (int i = 0; i < 6; ++i) {
    uint32_t a = 0u, bb = (uint32_t)i;
    tf2x32(0u, 7u, a, bb);
    fk0[i] = a; fk1[i] = bb;
  }

  pos_add_kernel<<<NTOT / 256, 256, 0, stream>>>(x, cur);

  for (int ci = 0; ci < 4; ++ci) {
    norm_dw_kernel<true><<<NB * NC, 64, 0, stream>>>(cur, bufB, dw_w + ci * NC * 7, dw_b + ci * NC);
    gemm128_kernel<0, false><<<dim3(8, 2, NB), 256, 0, stream>>>(
        pw_w + (size_t)ci * NC * NC, bufB, cur, pw_b + ci * NC, cur, fk0[ci], fk1[ci]);
  }

  norm_dw_kernel<false><<<NB * NC, 64, 0, stream>>>(cur, bufA, nullptr, nullptr);
  qkv_kernel<<<dim3(8, 6, NB), 256, 0, stream>>>(Wq, Wk, Wv, bufA, qkv);
  attn_kernel<<<NH * NB * 4, 512, 0, stream>>>(qkv, bufB);
  gemm128_kernel<1, true><<<dim3(8, 2, NB), 256, 0, stream>>>(
      Wo, bufB, cur, nullptr, cur, fk0[4], fk1[4]);

  norm_dw_kernel<false><<<NB * NC, 64, 0, stream>>>(cur, bufA, nullptr, nullptr);
  gemm128_kernel<2, true><<<dim3(8, 2, NB), 256, 0, stream>>>(
      W, bufA, out, nullptr, cur, fk0[5], fk1[5]);
}